// Round 1
// baseline (902.541 us; speedup 1.0000x reference)
//
#include <hip/hip_runtime.h>
#include <math.h>

// Problem constants (setup_inputs): B=8, C=256, H=64, W=256
#define BH_ 64
#define BW_ 256
constexpr int TPX = 32;            // pixels per block tile (one row segment)
constexpr size_t HW = (size_t)BH_ * BW_;   // 16384

// ---------------------------------------------------------------------------
// Fused depthwise 3x3 + pointwise (CI->CO) + optional ReLU.
// Block: 256 threads, tile = 32 pixels of one row, all CI channels.
// Phase A: dw outputs -> LDS dwbuf[CI][32]
// Phase B: register-blocked GEMM, weights transposed into LDS chunks.
// ---------------------------------------------------------------------------
template<int CI, int CO, int CPT, int PPT, bool RELU>
__global__ __launch_bounds__(256)
void dsconv_kernel(const float* __restrict__ xin,   // (kc, CI, H, W)
                   const float* __restrict__ dww,   // (CI, 9)
                   const float* __restrict__ dwb,   // (CI)
                   const float* __restrict__ pww,   // (CO, CI)
                   const float* __restrict__ pwb,   // (CO)
                   float* __restrict__ out)         // (kc, CO, H, W)
{
    constexpr int NPX_T = TPX / PPT;   // threads along px
    constexpr int NCO_T = CO / CPT;    // threads along co
    static_assert(NPX_T * NCO_T == 256, "thread grid mismatch");
    static_assert(PPT == 4, "epilogue assumes float4");
    constexpr int WCHUNK = 64;
    static_assert(CI % WCHUNK == 0, "CI chunking");
    constexpr int WSTRIDE = CO + 4;    // pad, keeps rows 16B-aligned

    __shared__ float dwbuf[CI][TPX];
    __shared__ float wbuf[WCHUNK][WSTRIDE];

    const int t   = threadIdx.x;
    const int bid = blockIdx.x;
    const int jt  = bid & 7;           // W/TPX = 8
    const int i   = (bid >> 3) & 63;   // H = 64
    const int b   = bid >> 9;          // image within chunk
    const int j0  = jt * TPX;

    // ---- Phase A: depthwise 3x3 ----
    {
        const int px  = t & 31;
        const int cig = t >> 5;        // 8 channels per pass
        const int j   = j0 + px;
        for (int ci = cig; ci < CI; ci += 8) {
            const float* xp = xin + (((size_t)b * CI + ci) * BH_) * BW_;
            const float* wk = dww + ci * 9;
            float acc = dwb[ci];
            #pragma unroll
            for (int di = -1; di <= 1; ++di) {
                int ii = i + di;
                if (ii < 0 || ii >= BH_) continue;
                const float* xr = xp + (size_t)ii * BW_;
                #pragma unroll
                for (int dj = -1; dj <= 1; ++dj) {
                    int jj = j + dj;
                    if (jj < 0 || jj >= BW_) continue;
                    acc += xr[jj] * wk[(di + 1) * 3 + (dj + 1)];
                }
            }
            dwbuf[ci][px] = acc;
        }
    }

    // ---- Phase B: pointwise GEMM ----
    const int px_t = t % NPX_T;
    const int co_t = t / NPX_T;
    const int co0  = co_t * CPT;
    const int p0   = px_t * PPT;

    float acc[CPT][PPT];
    #pragma unroll
    for (int ii = 0; ii < CPT; ++ii) {
        float bv = pwb[co0 + ii];
        #pragma unroll
        for (int jj = 0; jj < PPT; ++jj) acc[ii][jj] = bv;
    }

    for (int cc = 0; cc < CI; cc += WCHUNK) {
        __syncthreads();   // dwbuf ready (first iter) / wbuf readers done (later)
        // load transposed weight chunk: pww[co][cc+ciw] -> wbuf[ciw][co]
        for (int idx = t; idx < WCHUNK * CO; idx += 256) {
            int ciw = idx & (WCHUNK - 1);
            int co  = idx / WCHUNK;
            wbuf[ciw][co] = pww[co * CI + cc + ciw];
        }
        __syncthreads();
        #pragma unroll 4
        for (int ci = 0; ci < WCHUNK; ++ci) {
            float wv[CPT];
            if constexpr (CPT == 4) {
                float4 wq = *reinterpret_cast<const float4*>(&wbuf[ci][co0]);
                wv[0] = wq.x; wv[1] = wq.y; wv[2] = wq.z; wv[3] = wq.w;
            } else if constexpr (CPT == 2) {
                float2 wq = *reinterpret_cast<const float2*>(&wbuf[ci][co0]);
                wv[0] = wq.x; wv[1] = wq.y;
            } else {
                wv[0] = wbuf[ci][co0];
            }
            float4 dq = *reinterpret_cast<const float4*>(&dwbuf[cc + ci][p0]);
            float dv[4] = {dq.x, dq.y, dq.z, dq.w};
            #pragma unroll
            for (int ii = 0; ii < CPT; ++ii)
                #pragma unroll
                for (int jj = 0; jj < PPT; ++jj)
                    acc[ii][jj] += wv[ii] * dv[jj];
        }
    }

    // ---- epilogue ----
    #pragma unroll
    for (int ii = 0; ii < CPT; ++ii) {
        float4 v;
        v.x = RELU ? fmaxf(acc[ii][0], 0.f) : acc[ii][0];
        v.y = RELU ? fmaxf(acc[ii][1], 0.f) : acc[ii][1];
        v.z = RELU ? fmaxf(acc[ii][2], 0.f) : acc[ii][2];
        v.w = RELU ? fmaxf(acc[ii][3], 0.f) : acc[ii][3];
        float* op = out + (((size_t)b * CO + co0 + ii) * BH_ + i) * BW_ + j0 + p0;
        *reinterpret_cast<float4*>(op) = v;
    }
}

// ---------------------------------------------------------------------------
// Final fused kernel: dw4(32ch) + pw(32->9) + softmax + char_attn write +
// dynamic 3x3 conv over the 256 channels of x.
// ---------------------------------------------------------------------------
__global__ __launch_bounds__(256)
void final_kernel(const float* __restrict__ x,    // (kc,256,H,W)
                  const float* __restrict__ a3,   // (kc,32,H,W)
                  const float* __restrict__ dww,  // (32,9)
                  const float* __restrict__ dwb,  // (32)
                  const float* __restrict__ pww,  // (9,32)
                  const float* __restrict__ pwb,  // (9)
                  float* __restrict__ out,        // (kc,256,H,W)
                  float* __restrict__ chat)       // (kc,H,W,9)
{
    __shared__ float dwbuf[32][TPX];
    __shared__ float att[9][TPX];

    const int t   = threadIdx.x;
    const int bid = blockIdx.x;
    const int jt  = bid & 7;
    const int i   = (bid >> 3) & 63;
    const int b   = bid >> 9;
    const int j0  = jt * TPX;
    const int px  = t & 31;

    // ---- dw4 on a3 ----
    {
        const int cig = t >> 5;
        const int j   = j0 + px;
        for (int ci = cig; ci < 32; ci += 8) {
            const float* xp = a3 + (((size_t)b * 32 + ci) * BH_) * BW_;
            const float* wk = dww + ci * 9;
            float acc = dwb[ci];
            #pragma unroll
            for (int di = -1; di <= 1; ++di) {
                int ii = i + di;
                if (ii < 0 || ii >= BH_) continue;
                const float* xr = xp + (size_t)ii * BW_;
                #pragma unroll
                for (int dj = -1; dj <= 1; ++dj) {
                    int jj = j + dj;
                    if (jj < 0 || jj >= BW_) continue;
                    acc += xr[jj] * wk[(di + 1) * 3 + (dj + 1)];
                }
            }
            dwbuf[ci][px] = acc;
        }
    }
    __syncthreads();

    // ---- logits (9 x 32 px) ----
    {
        const int co = t >> 5;   // 0..7
        float acc = pwb[co];
        #pragma unroll
        for (int ci = 0; ci < 32; ++ci)
            acc += pww[co * 32 + ci] * dwbuf[ci][px];
        att[co][px] = acc;
    }
    if (t < 32) {                // co = 8
        float acc = pwb[8];
        #pragma unroll
        for (int ci = 0; ci < 32; ++ci)
            acc += pww[8 * 32 + ci] * dwbuf[ci][t];
        att[8][t] = acc;
    }
    __syncthreads();

    // ---- softmax over the 9 taps (threads 0..31 own one pixel each) ----
    if (t < 32) {
        float v[9];
        float m = -1e30f;
        #pragma unroll
        for (int k = 0; k < 9; ++k) { v[k] = att[k][t]; m = fmaxf(m, v[k]); }
        float s = 0.f;
        #pragma unroll
        for (int k = 0; k < 9; ++k) { v[k] = __expf(v[k] - m); s += v[k]; }
        float inv = 1.f / s;
        #pragma unroll
        for (int k = 0; k < 9; ++k) att[k][t] = v[k] * inv;
    }
    __syncthreads();

    // ---- char_attn: (b,i,j,9) contiguous -> coalesced ----
    {
        size_t base = (((size_t)b * BH_ + i) * BW_ + j0) * 9;
        for (int idx = t; idx < TPX * 9; idx += 256)
            chat[base + idx] = att[idx % 9][idx / 9];
    }

    // ---- dynamic 3x3 conv over 256 channels ----
    {
        const int j = j0 + px;
        for (int c = t >> 5; c < 256; c += 8) {
            const float* xp = x + (((size_t)b * 256 + c) * BH_) * BW_;
            float acc = 0.f;
            #pragma unroll
            for (int di = -1; di <= 1; ++di) {
                int ii = i + di;
                if (ii < 0 || ii >= BH_) continue;
                const float* xr = xp + (size_t)ii * BW_;
                #pragma unroll
                for (int dj = -1; dj <= 1; ++dj) {
                    int jj = j + dj;
                    if (jj < 0 || jj >= BW_) continue;
                    acc += xr[jj] * att[(di + 1) * 3 + (dj + 1)][px];
                }
            }
            out[(((size_t)b * 256 + c) * BH_ + i) * BW_ + j] = acc;
        }
    }
}

// ---------------------------------------------------------------------------
extern "C" void kernel_launch(void* const* d_in, const int* in_sizes, int n_in,
                              void* d_out, int out_size, void* d_ws, size_t ws_size,
                              hipStream_t stream)
{
    const float* x    = (const float*)d_in[0];
    const float* dw1w = (const float*)d_in[1];
    const float* dw1b = (const float*)d_in[2];
    const float* pw1w = (const float*)d_in[3];
    const float* pw1b = (const float*)d_in[4];
    const float* dw2w = (const float*)d_in[5];
    const float* dw2b = (const float*)d_in[6];
    const float* pw2w = (const float*)d_in[7];
    const float* pw2b = (const float*)d_in[8];
    const float* dw3w = (const float*)d_in[9];
    const float* dw3b = (const float*)d_in[10];
    const float* pw3w = (const float*)d_in[11];
    const float* pw3b = (const float*)d_in[12];
    const float* dw4w = (const float*)d_in[13];
    const float* dw4b = (const float*)d_in[14];
    const float* pw4w = (const float*)d_in[15];
    const float* pw4b = (const float*)d_in[16];

    float* outp = (float*)d_out;
    float* chat = outp + (size_t)8 * 256 * HW;   // out is (8,256,H,W) then char_attn

    // ws layout: a1 (kc*128*HW) at 0, a2 (kc*64*HW) after; a3 reuses a1's space.
    // Pick the largest image-chunk kc whose ws footprint fits.
    int kmax = 1;
    for (int k = 8; k >= 1; k >>= 1) {
        size_t need = (size_t)k * (128 + 64) * HW * sizeof(float);
        if (need <= ws_size) { kmax = k; break; }
    }

    float* a1 = (float*)d_ws;
    float* a2 = a1 + (size_t)kmax * 128 * HW;
    float* a3 = a1;  // layer3 output overwrites dead a1

    for (int b0 = 0; b0 < 8; b0 += kmax) {
        int kc = (8 - b0 < kmax) ? (8 - b0) : kmax;
        const float* xb = x + (size_t)b0 * 256 * HW;
        int grid = kc * 512;   // H * (W/TPX) = 64*8 blocks per image

        dsconv_kernel<256, 128, 4, 4, true><<<grid, 256, 0, stream>>>(
            xb, dw1w, dw1b, pw1w, pw1b, a1);
        dsconv_kernel<128, 64, 2, 4, true><<<grid, 256, 0, stream>>>(
            a1, dw2w, dw2b, pw2w, pw2b, a2);
        dsconv_kernel<64, 32, 1, 4, true><<<grid, 256, 0, stream>>>(
            a2, dw3w, dw3b, pw3w, pw3b, a3);
        final_kernel<<<grid, 256, 0, stream>>>(
            xb, a3, dw4w, dw4b, pw4w, pw4b,
            outp + (size_t)b0 * 256 * HW, chat + (size_t)b0 * HW * 9);
    }
}

// Round 2
// 447.600 us; speedup vs baseline: 2.0164x; 2.0164x over previous
//
#include <hip/hip_runtime.h>
#include <math.h>

// Problem constants (setup_inputs): B=8, C=256, H=64, W=256
#define BH_ 64
#define BW_ 256
constexpr size_t HW = (size_t)BH_ * BW_;   // 16384

// ---------------------------------------------------------------------------
// Weight transpose: pww (CO,CI) -> wT (CI,CO), for layers 1..3.
// ---------------------------------------------------------------------------
__global__ __launch_bounds__(256)
void transpose_w_kernel(const float* __restrict__ p1,  // (128,256)
                        const float* __restrict__ p2,  // (64,128)
                        const float* __restrict__ p3,  // (32,64)
                        float* __restrict__ w1,        // (256,128)
                        float* __restrict__ w2,        // (128,64)
                        float* __restrict__ w3)        // (64,32)
{
    int idx = blockIdx.x * 256 + threadIdx.x;
    if (idx < 128 * 256) {
        int ci = idx / 128, co = idx % 128;
        w1[idx] = p1[co * 256 + ci];
    } else if (idx < 128 * 256 + 64 * 128) {
        int r = idx - 128 * 256;
        int ci = r / 64, co = r % 64;
        w2[r] = p2[co * 128 + ci];
    } else if (idx < 128 * 256 + 64 * 128 + 32 * 64) {
        int r = idx - (128 * 256 + 64 * 128);
        int ci = r / 32, co = r % 32;
        w3[r] = p3[co * 64 + ci];
    }
}

// ---------------------------------------------------------------------------
// Fused depthwise 3x3 + pointwise (CI->CO) + ReLU, GEMM-structured.
// Block: 256 threads. Tile: 64 px (one row segment) x CO outputs.
// CI processed in chunks of 32: dw -> LDS (bf-free fp32), then register GEMM.
//   thread map (GEMM): px_g = t&15 (4 px each), co_g = t>>4 (CPT co each)
//   thread map (dw):   ci_local = t>>3 (1 ch), g = t&7 (8 px each)
// ---------------------------------------------------------------------------
template<int CI, int CO, int CPT>
__global__ __launch_bounds__(256, 4)
void dsconv_kernel(const float* __restrict__ xin,   // (kc, CI, H, W)
                   const float* __restrict__ dww,   // (CI, 9)
                   const float* __restrict__ dwb,   // (CI)
                   const float* __restrict__ wT,    // (CI, CO) transposed pw
                   const float* __restrict__ pwb,   // (CO)
                   float* __restrict__ out)         // (kc, CO, H, W)
{
    constexpr int CIC = 32;                 // CI chunk
    constexpr int PX  = 64;                 // pixels per tile
    static_assert(CO / CPT == 16, "co groups must be 16");
    static_assert(CI % CIC == 0, "CI chunking");

    __shared__ float dwbuf[CIC * PX];       // 8 KB
    __shared__ float wbuf[CIC * CO];        // 4..16 KB

    const int t   = threadIdx.x;
    const int bid = blockIdx.x;
    const int jt  = bid & 3;                // W/PX = 4
    const int i   = (bid >> 2) & 63;        // H
    const int b   = bid >> 8;               // image in chunk
    const int j0  = jt * PX;

    const int px_g = t & 15;
    const int co_g = t >> 4;
    const int co0  = co_g * CPT;
    const int p0   = px_g * 4;

    const int ci_local = t >> 3;
    const int g        = t & 7;
    const int jq       = j0 + g * 8;

    float acc[CPT][4];
    #pragma unroll
    for (int ii = 0; ii < CPT; ++ii) {
        float bv = pwb[co0 + ii];
        #pragma unroll
        for (int jj = 0; jj < 4; ++jj) acc[ii][jj] = bv;
    }

    for (int cc = 0; cc < CI; cc += CIC) {
        __syncthreads();   // previous chunk's readers done

        // ---- weight chunk: contiguous copy (coalesced, conflict-free) ----
        {
            const float* src = wT + (size_t)cc * CO;
            #pragma unroll
            for (int idx = t * 4; idx < CIC * CO; idx += 1024)
                *reinterpret_cast<float4*>(&wbuf[idx]) =
                    *reinterpret_cast<const float4*>(&src[idx]);
        }

        // ---- depthwise 3x3 for this chunk: 8 px per thread, sliding window ----
        {
            const int ci = cc + ci_local;
            const float* wk = dww + ci * 9;
            float w[9];
            #pragma unroll
            for (int k = 0; k < 9; ++k) w[k] = wk[k];
            float o[8];
            float bv = dwb[ci];
            #pragma unroll
            for (int e = 0; e < 8; ++e) o[e] = bv;

            const float* xp = xin + ((size_t)b * CI + ci) * HW;
            #pragma unroll
            for (int di = -1; di <= 1; ++di) {
                int ii2 = i + di;
                if ((unsigned)ii2 < (unsigned)BH_) {
                    const float* xr = xp + (size_t)ii2 * BW_ + jq;
                    float v[10];
                    v[0] = (jq > 0) ? xr[-1] : 0.f;
                    float4 A = *reinterpret_cast<const float4*>(xr);
                    float4 Bq = *reinterpret_cast<const float4*>(xr + 4);
                    v[1] = A.x; v[2] = A.y; v[3] = A.z; v[4] = A.w;
                    v[5] = Bq.x; v[6] = Bq.y; v[7] = Bq.z; v[8] = Bq.w;
                    v[9] = (jq + 8 < BW_) ? xr[8] : 0.f;
                    const float w0 = w[(di + 1) * 3 + 0];
                    const float w1 = w[(di + 1) * 3 + 1];
                    const float w2 = w[(di + 1) * 3 + 2];
                    #pragma unroll
                    for (int e = 0; e < 8; ++e)
                        o[e] += w0 * v[e] + w1 * v[e + 1] + w2 * v[e + 2];
                }
            }
            float4* dst = reinterpret_cast<float4*>(&dwbuf[ci_local * PX + g * 8]);
            dst[0] = make_float4(o[0], o[1], o[2], o[3]);
            dst[1] = make_float4(o[4], o[5], o[6], o[7]);
        }

        __syncthreads();   // dwbuf + wbuf ready

        // ---- register GEMM over the chunk ----
        #pragma unroll 4
        for (int k = 0; k < CIC; ++k) {
            float4 dq = *reinterpret_cast<const float4*>(&dwbuf[k * PX + p0]);
            float dv[4] = {dq.x, dq.y, dq.z, dq.w};
            float wv[CPT];
            if constexpr (CPT == 8) {
                float4 wq0 = *reinterpret_cast<const float4*>(&wbuf[k * CO + co0]);
                float4 wq1 = *reinterpret_cast<const float4*>(&wbuf[k * CO + co0 + 4]);
                wv[0] = wq0.x; wv[1] = wq0.y; wv[2] = wq0.z; wv[3] = wq0.w;
                wv[4] = wq1.x; wv[5] = wq1.y; wv[6] = wq1.z; wv[7] = wq1.w;
            } else if constexpr (CPT == 4) {
                float4 wq = *reinterpret_cast<const float4*>(&wbuf[k * CO + co0]);
                wv[0] = wq.x; wv[1] = wq.y; wv[2] = wq.z; wv[3] = wq.w;
            } else {
                float2 wq = *reinterpret_cast<const float2*>(&wbuf[k * CO + co0]);
                wv[0] = wq.x; wv[1] = wq.y;
            }
            #pragma unroll
            for (int ii = 0; ii < CPT; ++ii)
                #pragma unroll
                for (int jj = 0; jj < 4; ++jj)
                    acc[ii][jj] += wv[ii] * dv[jj];
        }
    }

    // ---- epilogue: ReLU + coalesced float4 stores ----
    #pragma unroll
    for (int ii = 0; ii < CPT; ++ii) {
        float4 v;
        v.x = fmaxf(acc[ii][0], 0.f);
        v.y = fmaxf(acc[ii][1], 0.f);
        v.z = fmaxf(acc[ii][2], 0.f);
        v.w = fmaxf(acc[ii][3], 0.f);
        float* op = out + (((size_t)b * CO + co0 + ii) * BH_ + i) * BW_ + j0 + p0;
        *reinterpret_cast<float4*>(op) = v;
    }
}

// ---------------------------------------------------------------------------
// Final fused kernel: dw4(32ch) + pw(32->9) + softmax + char_attn write +
// dynamic 3x3 conv over the 256 channels of x.  Tile: 32 px of one row.
// ---------------------------------------------------------------------------
__global__ __launch_bounds__(256)
void final_kernel(const float* __restrict__ x,    // (kc,256,H,W)
                  const float* __restrict__ a3,   // (kc,32,H,W)
                  const float* __restrict__ dww,  // (32,9)
                  const float* __restrict__ dwb,  // (32)
                  const float* __restrict__ pww,  // (9,32)
                  const float* __restrict__ pwb,  // (9)
                  float* __restrict__ out,        // (kc,256,H,W)
                  float* __restrict__ chat)       // (kc,H,W,9)
{
    constexpr int TPX = 32;
    __shared__ float dwbuf[32][TPX];
    __shared__ float att[9][TPX];

    const int t   = threadIdx.x;
    const int bid = blockIdx.x;
    const int jt  = bid & 7;
    const int i   = (bid >> 3) & 63;
    const int b   = bid >> 9;
    const int j0  = jt * TPX;
    const int px  = t & 31;

    // ---- dw4 on a3 ----
    {
        const int cig = t >> 5;
        const int j   = j0 + px;
        for (int ci = cig; ci < 32; ci += 8) {
            const float* xp = a3 + (((size_t)b * 32 + ci) * BH_) * BW_;
            const float* wk = dww + ci * 9;
            float acc = dwb[ci];
            #pragma unroll
            for (int di = -1; di <= 1; ++di) {
                int ii = i + di;
                if (ii < 0 || ii >= BH_) continue;
                const float* xr = xp + (size_t)ii * BW_;
                #pragma unroll
                for (int dj = -1; dj <= 1; ++dj) {
                    int jj = j + dj;
                    if (jj < 0 || jj >= BW_) continue;
                    acc += xr[jj] * wk[(di + 1) * 3 + (dj + 1)];
                }
            }
            dwbuf[ci][px] = acc;
        }
    }
    __syncthreads();

    // ---- logits (9 x 32 px) ----
    {
        const int co = t >> 5;   // 0..7
        float acc = pwb[co];
        #pragma unroll
        for (int ci = 0; ci < 32; ++ci)
            acc += pww[co * 32 + ci] * dwbuf[ci][px];
        att[co][px] = acc;
    }
    if (t < 32) {                // co = 8
        float acc = pwb[8];
        #pragma unroll
        for (int ci = 0; ci < 32; ++ci)
            acc += pww[8 * 32 + ci] * dwbuf[ci][t];
        att[8][t] = acc;
    }
    __syncthreads();

    // ---- softmax over the 9 taps (threads 0..31 own one pixel each) ----
    if (t < 32) {
        float v[9];
        float m = -1e30f;
        #pragma unroll
        for (int k = 0; k < 9; ++k) { v[k] = att[k][t]; m = fmaxf(m, v[k]); }
        float s = 0.f;
        #pragma unroll
        for (int k = 0; k < 9; ++k) { v[k] = __expf(v[k] - m); s += v[k]; }
        float inv = 1.f / s;
        #pragma unroll
        for (int k = 0; k < 9; ++k) att[k][t] = v[k] * inv;
    }
    __syncthreads();

    // ---- char_attn: (b,i,j,9) contiguous -> coalesced ----
    {
        size_t base = (((size_t)b * BH_ + i) * BW_ + j0) * 9;
        for (int idx = t; idx < TPX * 9; idx += 256)
            chat[base + idx] = att[idx % 9][idx / 9];
    }

    // ---- dynamic 3x3 conv over 256 channels ----
    {
        const int j = j0 + px;
        for (int c = t >> 5; c < 256; c += 8) {
            const float* xp = x + (((size_t)b * 256 + c) * BH_) * BW_;
            float acc = 0.f;
            #pragma unroll
            for (int di = -1; di <= 1; ++di) {
                int ii = i + di;
                if (ii < 0 || ii >= BH_) continue;
                const float* xr = xp + (size_t)ii * BW_;
                #pragma unroll
                for (int dj = -1; dj <= 1; ++dj) {
                    int jj = j + dj;
                    if (jj < 0 || jj >= BW_) continue;
                    acc += xr[jj] * att[(di + 1) * 3 + (dj + 1)][px];
                }
            }
            out[(((size_t)b * 256 + c) * BH_ + i) * BW_ + j] = acc;
        }
    }
}

// ---------------------------------------------------------------------------
extern "C" void kernel_launch(void* const* d_in, const int* in_sizes, int n_in,
                              void* d_out, int out_size, void* d_ws, size_t ws_size,
                              hipStream_t stream)
{
    const float* x    = (const float*)d_in[0];
    const float* dw1w = (const float*)d_in[1];
    const float* dw1b = (const float*)d_in[2];
    const float* pw1w = (const float*)d_in[3];
    const float* pw1b = (const float*)d_in[4];
    const float* dw2w = (const float*)d_in[5];
    const float* dw2b = (const float*)d_in[6];
    const float* pw2w = (const float*)d_in[7];
    const float* pw2b = (const float*)d_in[8];
    const float* dw3w = (const float*)d_in[9];
    const float* dw3b = (const float*)d_in[10];
    const float* pw3w = (const float*)d_in[11];
    const float* pw3b = (const float*)d_in[12];
    const float* dw4w = (const float*)d_in[13];
    const float* dw4b = (const float*)d_in[14];
    const float* pw4w = (const float*)d_in[15];
    const float* pw4b = (const float*)d_in[16];

    float* outp = (float*)d_out;
    float* chat = outp + (size_t)8 * 256 * HW;   // out (8,256,H,W), then char_attn

    // ws layout: [wt1 | wt2 | wt3 | a1 | a2], a3 aliases a1.
    constexpr size_t WT1 = 256 * 128, WT2 = 128 * 64, WT3 = 64 * 32;
    constexpr size_t WTS = WT1 + WT2 + WT3;           // 43008 floats
    float* wt1 = (float*)d_ws;
    float* wt2 = wt1 + WT1;
    float* wt3 = wt2 + WT2;
    float* abase = wt3 + WT3;

    int kmax = 1;
    for (int k = 8; k >= 1; k >>= 1) {
        size_t need = (WTS + (size_t)k * (128 + 64) * HW) * sizeof(float);
        if (need <= ws_size) { kmax = k; break; }
    }
    float* a1 = abase;
    float* a2 = a1 + (size_t)kmax * 128 * HW;
    float* a3 = a1;   // layer-3 output reuses a1's (dead) space

    transpose_w_kernel<<<(128 * 256 + 64 * 128 + 32 * 64 + 255) / 256, 256, 0, stream>>>(
        pw1w, pw2w, pw3w, wt1, wt2, wt3);

    for (int b0 = 0; b0 < 8; b0 += kmax) {
        int kc = (8 - b0 < kmax) ? (8 - b0) : kmax;
        const float* xb = x + (size_t)b0 * 256 * HW;
        int grid64 = kc * 256;   // H * (W/64) = 256 blocks per image
        int grid32 = kc * 512;   // final kernel: 32-px tiles

        dsconv_kernel<256, 128, 8><<<grid64, 256, 0, stream>>>(
            xb, dw1w, dw1b, wt1, pw1b, a1);
        dsconv_kernel<128, 64, 4><<<grid64, 256, 0, stream>>>(
            a1, dw2w, dw2b, wt2, pw2b, a2);
        dsconv_kernel<64, 32, 2><<<grid64, 256, 0, stream>>>(
            a2, dw3w, dw3b, wt3, pw3b, a3);
        final_kernel<<<grid32, 256, 0, stream>>>(
            xb, a3, dw4w, dw4b, pw4w, pw4b,
            outp + (size_t)b0 * 256 * HW, chat + (size_t)b0 * HW * 9);
    }
}

// Round 3
// 361.946 us; speedup vs baseline: 2.4936x; 1.2366x over previous
//
#include <hip/hip_runtime.h>
#include <math.h>

// Problem constants (setup_inputs): B=8, C=256, H=64, W=256
#define BH_ 64
#define BW_ 256
constexpr size_t HW = (size_t)BH_ * BW_;   // 16384

// ---------------------------------------------------------------------------
// Weight transpose: pww (CO,CI) -> wT (CI,CO), for layers 1..3.
// ---------------------------------------------------------------------------
__global__ __launch_bounds__(256)
void transpose_w_kernel(const float* __restrict__ p1,  // (128,256)
                        const float* __restrict__ p2,  // (64,128)
                        const float* __restrict__ p3,  // (32,64)
                        float* __restrict__ w1,        // (256,128)
                        float* __restrict__ w2,        // (128,64)
                        float* __restrict__ w3)        // (64,32)
{
    int idx = blockIdx.x * 256 + threadIdx.x;
    if (idx < 128 * 256) {
        int ci = idx / 128, co = idx % 128;
        w1[idx] = p1[co * 256 + ci];
    } else if (idx < 128 * 256 + 64 * 128) {
        int r = idx - 128 * 256;
        int ci = r / 64, co = r % 64;
        w2[r] = p2[co * 128 + ci];
    } else if (idx < 128 * 256 + 64 * 128 + 32 * 64) {
        int r = idx - (128 * 256 + 64 * 128);
        int ci = r / 32, co = r % 32;
        w3[r] = p3[co * 64 + ci];
    }
}

// ---------------------------------------------------------------------------
// Fused depthwise 3x3 + pointwise (CI->CO) + ReLU, GEMM-structured.
// (unchanged from round 2)
// ---------------------------------------------------------------------------
template<int CI, int CO, int CPT>
__global__ __launch_bounds__(256, 4)
void dsconv_kernel(const float* __restrict__ xin,   // (kc, CI, H, W)
                   const float* __restrict__ dww,   // (CI, 9)
                   const float* __restrict__ dwb,   // (CI)
                   const float* __restrict__ wT,    // (CI, CO) transposed pw
                   const float* __restrict__ pwb,   // (CO)
                   float* __restrict__ out)         // (kc, CO, H, W)
{
    constexpr int CIC = 32;                 // CI chunk
    constexpr int PX  = 64;                 // pixels per tile
    static_assert(CO / CPT == 16, "co groups must be 16");
    static_assert(CI % CIC == 0, "CI chunking");

    __shared__ float dwbuf[CIC * PX];       // 8 KB
    __shared__ float wbuf[CIC * CO];        // 4..16 KB

    const int t   = threadIdx.x;
    const int bid = blockIdx.x;
    const int jt  = bid & 3;                // W/PX = 4
    const int i   = (bid >> 2) & 63;        // H
    const int b   = bid >> 8;               // image in chunk
    const int j0  = jt * PX;

    const int px_g = t & 15;
    const int co_g = t >> 4;
    const int co0  = co_g * CPT;
    const int p0   = px_g * 4;

    const int ci_local = t >> 3;
    const int g        = t & 7;
    const int jq       = j0 + g * 8;

    float acc[CPT][4];
    #pragma unroll
    for (int ii = 0; ii < CPT; ++ii) {
        float bv = pwb[co0 + ii];
        #pragma unroll
        for (int jj = 0; jj < 4; ++jj) acc[ii][jj] = bv;
    }

    for (int cc = 0; cc < CI; cc += CIC) {
        __syncthreads();   // previous chunk's readers done

        // ---- weight chunk: contiguous copy (coalesced, conflict-free) ----
        {
            const float* src = wT + (size_t)cc * CO;
            #pragma unroll
            for (int idx = t * 4; idx < CIC * CO; idx += 1024)
                *reinterpret_cast<float4*>(&wbuf[idx]) =
                    *reinterpret_cast<const float4*>(&src[idx]);
        }

        // ---- depthwise 3x3 for this chunk: 8 px per thread, sliding window ----
        {
            const int ci = cc + ci_local;
            const float* wk = dww + ci * 9;
            float w[9];
            #pragma unroll
            for (int k = 0; k < 9; ++k) w[k] = wk[k];
            float o[8];
            float bv = dwb[ci];
            #pragma unroll
            for (int e = 0; e < 8; ++e) o[e] = bv;

            const float* xp = xin + ((size_t)b * CI + ci) * HW;
            #pragma unroll
            for (int di = -1; di <= 1; ++di) {
                int ii2 = i + di;
                if ((unsigned)ii2 < (unsigned)BH_) {
                    const float* xr = xp + (size_t)ii2 * BW_ + jq;
                    float v[10];
                    v[0] = (jq > 0) ? xr[-1] : 0.f;
                    float4 A = *reinterpret_cast<const float4*>(xr);
                    float4 Bq = *reinterpret_cast<const float4*>(xr + 4);
                    v[1] = A.x; v[2] = A.y; v[3] = A.z; v[4] = A.w;
                    v[5] = Bq.x; v[6] = Bq.y; v[7] = Bq.z; v[8] = Bq.w;
                    v[9] = (jq + 8 < BW_) ? xr[8] : 0.f;
                    const float w0 = w[(di + 1) * 3 + 0];
                    const float w1 = w[(di + 1) * 3 + 1];
                    const float w2 = w[(di + 1) * 3 + 2];
                    #pragma unroll
                    for (int e = 0; e < 8; ++e)
                        o[e] += w0 * v[e] + w1 * v[e + 1] + w2 * v[e + 2];
                }
            }
            float4* dst = reinterpret_cast<float4*>(&dwbuf[ci_local * PX + g * 8]);
            dst[0] = make_float4(o[0], o[1], o[2], o[3]);
            dst[1] = make_float4(o[4], o[5], o[6], o[7]);
        }

        __syncthreads();   // dwbuf + wbuf ready

        // ---- register GEMM over the chunk ----
        #pragma unroll 4
        for (int k = 0; k < CIC; ++k) {
            float4 dq = *reinterpret_cast<const float4*>(&dwbuf[k * PX + p0]);
            float dv[4] = {dq.x, dq.y, dq.z, dq.w};
            float wv[CPT];
            if constexpr (CPT == 8) {
                float4 wq0 = *reinterpret_cast<const float4*>(&wbuf[k * CO + co0]);
                float4 wq1 = *reinterpret_cast<const float4*>(&wbuf[k * CO + co0 + 4]);
                wv[0] = wq0.x; wv[1] = wq0.y; wv[2] = wq0.z; wv[3] = wq0.w;
                wv[4] = wq1.x; wv[5] = wq1.y; wv[6] = wq1.z; wv[7] = wq1.w;
            } else if constexpr (CPT == 4) {
                float4 wq = *reinterpret_cast<const float4*>(&wbuf[k * CO + co0]);
                wv[0] = wq.x; wv[1] = wq.y; wv[2] = wq.z; wv[3] = wq.w;
            } else {
                float2 wq = *reinterpret_cast<const float2*>(&wbuf[k * CO + co0]);
                wv[0] = wq.x; wv[1] = wq.y;
            }
            #pragma unroll
            for (int ii = 0; ii < CPT; ++ii)
                #pragma unroll
                for (int jj = 0; jj < 4; ++jj)
                    acc[ii][jj] += wv[ii] * dv[jj];
        }
    }

    // ---- epilogue: ReLU + coalesced float4 stores ----
    #pragma unroll
    for (int ii = 0; ii < CPT; ++ii) {
        float4 v;
        v.x = fmaxf(acc[ii][0], 0.f);
        v.y = fmaxf(acc[ii][1], 0.f);
        v.z = fmaxf(acc[ii][2], 0.f);
        v.w = fmaxf(acc[ii][3], 0.f);
        float* op = out + (((size_t)b * CO + co0 + ii) * BH_ + i) * BW_ + j0 + p0;
        *reinterpret_cast<float4*>(op) = v;
    }
}

// ---------------------------------------------------------------------------
// Final fused kernel, restructured: 64-px row tile.
// dw4 (sliding window) + pw(32->9) + softmax + char_attn + dynamic 3x3 conv
// with att in registers and float4 window loads.
//   dw4 map:    ci = t>>3 (32 ch), g = t&7 (8 px each)
//   dyn map:    c0 = t>>3 (8 ch strided by 32), g = t&7 (8 px each)
// ---------------------------------------------------------------------------
__global__ __launch_bounds__(256, 4)
void final_kernel(const float* __restrict__ x,    // (kc,256,H,W)
                  const float* __restrict__ a3,   // (kc,32,H,W)
                  const float* __restrict__ dww,  // (32,9)
                  const float* __restrict__ dwb,  // (32)
                  const float* __restrict__ pww,  // (9,32)
                  const float* __restrict__ pwb,  // (9)
                  float* __restrict__ out,        // (kc,256,H,W)
                  float* __restrict__ chat)       // (kc,H,W,9)
{
    constexpr int PX = 64;
    __shared__ float dwbuf[32 * PX];     // 8 KB
    __shared__ float attL[9][PX];        // 2.25 KB

    const int t   = threadIdx.x;
    const int bid = blockIdx.x;
    const int jt  = bid & 3;             // W/64 = 4
    const int i   = (bid >> 2) & 63;     // H
    const int b   = bid >> 8;
    const int j0  = jt * PX;
    const int g   = t & 7;
    const int jq  = j0 + g * 8;

    // ---- dw4 on a3: 32 ch x 64 px, sliding-window float4 ----
    {
        const int ci = t >> 3;
        const float* wk = dww + ci * 9;
        float w[9];
        #pragma unroll
        for (int k = 0; k < 9; ++k) w[k] = wk[k];
        float o[8];
        float bv = dwb[ci];
        #pragma unroll
        for (int e = 0; e < 8; ++e) o[e] = bv;

        const float* xp = a3 + ((size_t)b * 32 + ci) * HW;
        #pragma unroll
        for (int di = -1; di <= 1; ++di) {
            int ii2 = i + di;
            if ((unsigned)ii2 < (unsigned)BH_) {
                const float* xr = xp + (size_t)ii2 * BW_ + jq;
                float v[10];
                v[0] = (jq > 0) ? xr[-1] : 0.f;
                float4 A = *reinterpret_cast<const float4*>(xr);
                float4 Bq = *reinterpret_cast<const float4*>(xr + 4);
                v[1] = A.x; v[2] = A.y; v[3] = A.z; v[4] = A.w;
                v[5] = Bq.x; v[6] = Bq.y; v[7] = Bq.z; v[8] = Bq.w;
                v[9] = (jq + 8 < BW_) ? xr[8] : 0.f;
                const float w0 = w[(di + 1) * 3 + 0];
                const float w1 = w[(di + 1) * 3 + 1];
                const float w2 = w[(di + 1) * 3 + 2];
                #pragma unroll
                for (int e = 0; e < 8; ++e)
                    o[e] += w0 * v[e] + w1 * v[e + 1] + w2 * v[e + 2];
            }
        }
        float4* dst = reinterpret_cast<float4*>(&dwbuf[(t >> 3) * PX + g * 8]);
        dst[0] = make_float4(o[0], o[1], o[2], o[3]);
        dst[1] = make_float4(o[4], o[5], o[6], o[7]);
    }
    __syncthreads();

    // ---- logits: 9 co x 64 px ----
    for (int idx = t; idx < 9 * PX; idx += 256) {
        int co = idx >> 6;
        int px = idx & 63;
        float acc = pwb[co];
        #pragma unroll
        for (int ci = 0; ci < 32; ++ci)
            acc += pww[co * 32 + ci] * dwbuf[ci * PX + px];
        attL[co][px] = acc;
    }
    __syncthreads();

    // ---- softmax over 9 taps (threads 0..63 own one pixel each) ----
    if (t < PX) {
        float v[9];
        float m = -1e30f;
        #pragma unroll
        for (int k = 0; k < 9; ++k) { v[k] = attL[k][t]; m = fmaxf(m, v[k]); }
        float s = 0.f;
        #pragma unroll
        for (int k = 0; k < 9; ++k) { v[k] = __expf(v[k] - m); s += v[k]; }
        float inv = 1.f / s;
        #pragma unroll
        for (int k = 0; k < 9; ++k) attL[k][t] = v[k] * inv;
    }
    __syncthreads();

    // ---- char_attn: (b,i,j,9) contiguous ----
    {
        size_t base = (((size_t)b * BH_ + i) * BW_ + j0) * 9;
        for (int idx = t; idx < PX * 9; idx += 256)
            chat[base + idx] = attL[idx % 9][idx / 9];
    }

    // ---- att -> registers (reused across all channels) ----
    float ar[9][8];
    #pragma unroll
    for (int k = 0; k < 9; ++k) {
        float4 a0 = *reinterpret_cast<const float4*>(&attL[k][g * 8]);
        float4 a1 = *reinterpret_cast<const float4*>(&attL[k][g * 8 + 4]);
        ar[k][0] = a0.x; ar[k][1] = a0.y; ar[k][2] = a0.z; ar[k][3] = a0.w;
        ar[k][4] = a1.x; ar[k][5] = a1.y; ar[k][6] = a1.z; ar[k][7] = a1.w;
    }

    // ---- dynamic 3x3 conv: 8 channels x 8 px per thread ----
    const int c0 = t >> 3;
    for (int c = c0; c < 256; c += 32) {
        const float* xp = x + ((size_t)b * 256 + c) * HW;
        float v3[3][10];
        #pragma unroll
        for (int di = 0; di < 3; ++di) {
            int ii2 = i + di - 1;
            if ((unsigned)ii2 < (unsigned)BH_) {
                const float* xr = xp + (size_t)ii2 * BW_ + jq;
                v3[di][0] = (jq > 0) ? xr[-1] : 0.f;
                float4 A = *reinterpret_cast<const float4*>(xr);
                float4 Bq = *reinterpret_cast<const float4*>(xr + 4);
                v3[di][1] = A.x; v3[di][2] = A.y; v3[di][3] = A.z; v3[di][4] = A.w;
                v3[di][5] = Bq.x; v3[di][6] = Bq.y; v3[di][7] = Bq.z; v3[di][8] = Bq.w;
                v3[di][9] = (jq + 8 < BW_) ? xr[8] : 0.f;
            } else {
                #pragma unroll
                for (int e = 0; e < 10; ++e) v3[di][e] = 0.f;
            }
        }
        float o[8];
        #pragma unroll
        for (int e = 0; e < 8; ++e) o[e] = 0.f;
        #pragma unroll
        for (int di = 0; di < 3; ++di)
            #pragma unroll
            for (int dj = 0; dj < 3; ++dj)
                #pragma unroll
                for (int e = 0; e < 8; ++e)
                    o[e] += v3[di][e + dj] * ar[di * 3 + dj][e];
        float* op = out + ((size_t)b * 256 + c) * HW + (size_t)i * BW_ + jq;
        *reinterpret_cast<float4*>(op)     = make_float4(o[0], o[1], o[2], o[3]);
        *reinterpret_cast<float4*>(op + 4) = make_float4(o[4], o[5], o[6], o[7]);
    }
}

// ---------------------------------------------------------------------------
extern "C" void kernel_launch(void* const* d_in, const int* in_sizes, int n_in,
                              void* d_out, int out_size, void* d_ws, size_t ws_size,
                              hipStream_t stream)
{
    const float* x    = (const float*)d_in[0];
    const float* dw1w = (const float*)d_in[1];
    const float* dw1b = (const float*)d_in[2];
    const float* pw1w = (const float*)d_in[3];
    const float* pw1b = (const float*)d_in[4];
    const float* dw2w = (const float*)d_in[5];
    const float* dw2b = (const float*)d_in[6];
    const float* pw2w = (const float*)d_in[7];
    const float* pw2b = (const float*)d_in[8];
    const float* dw3w = (const float*)d_in[9];
    const float* dw3b = (const float*)d_in[10];
    const float* pw3w = (const float*)d_in[11];
    const float* pw3b = (const float*)d_in[12];
    const float* dw4w = (const float*)d_in[13];
    const float* dw4b = (const float*)d_in[14];
    const float* pw4w = (const float*)d_in[15];
    const float* pw4b = (const float*)d_in[16];

    float* outp = (float*)d_out;
    float* chat = outp + (size_t)8 * 256 * HW;   // out (8,256,H,W), then char_attn

    // ws layout: [wt1 | wt2 | wt3 | a1 | a2], a3 aliases a1.
    constexpr size_t WT1 = 256 * 128, WT2 = 128 * 64, WT3 = 64 * 32;
    constexpr size_t WTS = WT1 + WT2 + WT3;           // 43008 floats
    float* wt1 = (float*)d_ws;
    float* wt2 = wt1 + WT1;
    float* wt3 = wt2 + WT2;
    float* abase = wt3 + WT3;

    int kmax = 1;
    for (int k = 8; k >= 1; k >>= 1) {
        size_t need = (WTS + (size_t)k * (128 + 64) * HW) * sizeof(float);
        if (need <= ws_size) { kmax = k; break; }
    }
    float* a1 = abase;
    float* a2 = a1 + (size_t)kmax * 128 * HW;
    float* a3 = a1;   // layer-3 output reuses a1's (dead) space

    transpose_w_kernel<<<(128 * 256 + 64 * 128 + 32 * 64 + 255) / 256, 256, 0, stream>>>(
        pw1w, pw2w, pw3w, wt1, wt2, wt3);

    for (int b0 = 0; b0 < 8; b0 += kmax) {
        int kc = (8 - b0 < kmax) ? (8 - b0) : kmax;
        const float* xb = x + (size_t)b0 * 256 * HW;
        int grid64 = kc * 256;   // H * (W/64) = 256 blocks per image

        dsconv_kernel<256, 128, 8><<<grid64, 256, 0, stream>>>(
            xb, dw1w, dw1b, wt1, pw1b, a1);
        dsconv_kernel<128, 64, 4><<<grid64, 256, 0, stream>>>(
            a1, dw2w, dw2b, wt2, pw2b, a2);
        dsconv_kernel<64, 32, 2><<<grid64, 256, 0, stream>>>(
            a2, dw3w, dw3b, wt3, pw3b, a3);
        final_kernel<<<grid64, 256, 0, stream>>>(
            xb, a3, dw4w, dw4b, pw4w, pw4b,
            outp + (size_t)b0 * 256 * HW, chat + (size_t)b0 * HW * 9);
    }
}

// Round 4
// 283.664 us; speedup vs baseline: 3.1817x; 1.2760x over previous
//
#include <hip/hip_runtime.h>
#include <math.h>

// Problem constants (setup_inputs): B=8, C=256, H=64, W=256
#define BH_ 64
#define BW_ 256
constexpr size_t HW = (size_t)BH_ * BW_;   // 16384

using f32x4  = __attribute__((ext_vector_type(4))) float;
using short8 = __attribute__((ext_vector_type(8))) short;

__device__ __forceinline__ short f2bf(float f) {
    unsigned u = __float_as_uint(f);
    u += 0x7fffu + ((u >> 16) & 1u);     // RNE to bf16
    return (short)(u >> 16);
}

// ---------------------------------------------------------------------------
// Prep: pw1/pw2 -> bf16 (same (CO,CI) layout, k-contiguous for MFMA B);
//       pw3 -> fp32 transposed (CI,CO) for the fp32 layer-3 kernel.
// ---------------------------------------------------------------------------
__global__ __launch_bounds__(256)
void prep_kernel(const float* __restrict__ p1,   // (128,256)
                 const float* __restrict__ p2,   // (64,128)
                 const float* __restrict__ p3,   // (32,64)
                 short* __restrict__ wb1,        // (128,256) bf16
                 short* __restrict__ wb2,        // (64,128) bf16
                 float* __restrict__ wt3)        // (64,32) f32
{
    int idx = blockIdx.x * 256 + threadIdx.x;
    if (idx < 128 * 256) {
        wb1[idx] = f2bf(p1[idx]);
    } else if (idx < 128 * 256 + 64 * 128) {
        int r = idx - 128 * 256;
        wb2[r] = f2bf(p2[r]);
    } else if (idx < 128 * 256 + 64 * 128 + 32 * 64) {
        int r = idx - (128 * 256 + 64 * 128);
        int ci = r / 32, co = r % 32;
        wt3[r] = p3[co * 64 + ci];
    }
}

// ---------------------------------------------------------------------------
// MFMA depthwise-separable layer (bf16 GEMM, fp32 dw): layers 1 and 2.
// Block: 256 threads (4 waves). Tile: 64 px of one row x CO outputs.
// K (=CI) in chunks of 32. A=[px][ci] bf16 pad-40, B=[co][ci] bf16 pad-40,
// both XOR-swizzled (^((row>>3&7)<<3) in short units) -> <=2-way conflicts.
// mfma_f32_16x16x32_bf16: A m=lane&15,k=(lane>>4)*8+e; B n=lane&15 same k;
// D col(n)=lane&15, row(m)=(lane>>4)*4+r.
// ---------------------------------------------------------------------------
template<int CI, int CO>
__global__ __launch_bounds__(256, 4)
void dsconv_mfma(const float* __restrict__ xin,   // (kc, CI, H, W)
                 const float* __restrict__ dww,   // (CI, 9)
                 const float* __restrict__ dwb,   // (CI)
                 const short* __restrict__ wBf,   // (CO, CI) bf16
                 const float* __restrict__ pwb,   // (CO)
                 float* __restrict__ out)         // (kc, CO, H, W)
{
    constexpr int CIC = 32;
    constexpr int PX  = 64;
    constexpr int NT  = CO / 16;
    constexpr int WNT = NT / 4;            // n-tiles per wave (2 for L1, 1 for L2)
    constexpr int ST  = 40;                // padded row stride in shorts (80 B)
    static_assert(NT % 4 == 0, "CO must be multiple of 64");
    static_assert(CI % CIC == 0, "CI chunking");

    __shared__ short Abuf[PX * ST];        // 5 KB
    __shared__ short Bbuf[CO * ST];        // 10 KB (L1) / 5 KB (L2)

    const int t    = threadIdx.x;
    const int w    = t >> 6;
    const int lane = t & 63;
    const int bid  = blockIdx.x;
    const int jt   = bid & 3;              // W/64 = 4
    const int i    = (bid >> 2) & 63;      // H
    const int b    = bid >> 8;
    const int j0   = jt * PX;

    // dw mapping: one ci x 8 px per thread
    const int ci_l = t >> 3;               // 0..31
    const int g    = t & 7;
    const int jq   = j0 + g * 8;

    // mfma lane coords
    const int lm = lane & 15;
    const int kb = lane >> 4;

    f32x4 acc[4][WNT];
    #pragma unroll
    for (int q = 0; q < WNT; ++q) {
        float bv = pwb[(w * WNT + q) * 16 + lm];
        #pragma unroll
        for (int mt = 0; mt < 4; ++mt) {
            f32x4 z = {bv, bv, bv, bv};
            acc[mt][q] = z;
        }
    }

    for (int cc = 0; cc < CI; cc += CIC) {
        __syncthreads();   // previous chunk's MFMA reads done

        // ---- stage B chunk: (CO x 32) bf16, swizzled ----
        {
            constexpr int SPT = (CO * CIC) / 256;   // shorts/thread: 16 (L1) / 8 (L2)
            constexpr int TPR = CIC / SPT;          // threads/row: 2 (L1) / 4 (L2)
            const int co  = t / TPR;
            const int sub = t % TPR;
            const short* src = wBf + (size_t)co * CI + cc + sub * SPT;
            const int sbase = co * ST + sub * SPT;
            const int swz   = ((co >> 3) & 7) << 3;
            #pragma unroll
            for (int jj = 0; jj < SPT / 8; ++jj) {
                *reinterpret_cast<short8*>(&Bbuf[(sbase + jj * 8) ^ swz]) =
                    *reinterpret_cast<const short8*>(&src[jj * 8]);
            }
        }

        // ---- depthwise 3x3 chunk -> Abuf (bf16, swizzled) ----
        {
            const int ci = cc + ci_l;
            const float* wkp = dww + ci * 9;
            float wv[9];
            #pragma unroll
            for (int k = 0; k < 9; ++k) wv[k] = wkp[k];
            float o[8];
            float bv = dwb[ci];
            #pragma unroll
            for (int e = 0; e < 8; ++e) o[e] = bv;

            const float* xp = xin + ((size_t)b * CI + ci) * HW;
            #pragma unroll
            for (int di = -1; di <= 1; ++di) {
                int ii2 = i + di;
                if ((unsigned)ii2 < (unsigned)BH_) {
                    const float* xr = xp + (size_t)ii2 * BW_ + jq;
                    float v[10];
                    v[0] = (jq > 0) ? xr[-1] : 0.f;
                    float4 A = *reinterpret_cast<const float4*>(xr);
                    float4 Bq = *reinterpret_cast<const float4*>(xr + 4);
                    v[1] = A.x; v[2] = A.y; v[3] = A.z; v[4] = A.w;
                    v[5] = Bq.x; v[6] = Bq.y; v[7] = Bq.z; v[8] = Bq.w;
                    v[9] = (jq + 8 < BW_) ? xr[8] : 0.f;
                    const float w0 = wv[(di + 1) * 3 + 0];
                    const float w1 = wv[(di + 1) * 3 + 1];
                    const float w2 = wv[(di + 1) * 3 + 2];
                    #pragma unroll
                    for (int e = 0; e < 8; ++e)
                        o[e] += w0 * v[e] + w1 * v[e + 1] + w2 * v[e + 2];
                }
            }
            #pragma unroll
            for (int e = 0; e < 8; ++e) {
                int px = g * 8 + e;
                int sa = (px * ST + ci_l) ^ (((px >> 3) & 7) << 3);
                Abuf[sa] = f2bf(o[e]);
            }
        }

        __syncthreads();   // Abuf + Bbuf ready

        // ---- MFMA phase ----
        {
            short8 bfrag[WNT];
            #pragma unroll
            for (int q = 0; q < WNT; ++q) {
                int co = (w * WNT + q) * 16 + lm;
                int sa = (co * ST + kb * 8) ^ (((co >> 3) & 7) << 3);
                bfrag[q] = *reinterpret_cast<const short8*>(&Bbuf[sa]);
            }
            #pragma unroll
            for (int mt = 0; mt < 4; ++mt) {
                int px = mt * 16 + lm;
                int sa = (px * ST + kb * 8) ^ (((px >> 3) & 7) << 3);
                short8 af = *reinterpret_cast<const short8*>(&Abuf[sa]);
                #pragma unroll
                for (int q = 0; q < WNT; ++q)
                    acc[mt][q] = __builtin_amdgcn_mfma_f32_16x16x32_bf16(
                        af, bfrag[q], acc[mt][q], 0, 0, 0);
            }
        }
    }

    // ---- epilogue: ReLU + float4 stores (fully coalesced per co line) ----
    #pragma unroll
    for (int mt = 0; mt < 4; ++mt) {
        #pragma unroll
        for (int q = 0; q < WNT; ++q) {
            int co = (w * WNT + q) * 16 + lm;
            float* op = out + (((size_t)b * CO + co) * BH_ + i) * BW_
                        + j0 + mt * 16 + kb * 4;
            float4 v;
            v.x = fmaxf(acc[mt][q][0], 0.f);
            v.y = fmaxf(acc[mt][q][1], 0.f);
            v.z = fmaxf(acc[mt][q][2], 0.f);
            v.w = fmaxf(acc[mt][q][3], 0.f);
            *reinterpret_cast<float4*>(op) = v;
        }
    }
}

// ---------------------------------------------------------------------------
// fp32 depthwise-separable layer (layer 3 only), unchanged from round 3.
// ---------------------------------------------------------------------------
template<int CI, int CO, int CPT>
__global__ __launch_bounds__(256, 4)
void dsconv_kernel(const float* __restrict__ xin,
                   const float* __restrict__ dww,
                   const float* __restrict__ dwb,
                   const float* __restrict__ wT,    // (CI, CO) transposed pw
                   const float* __restrict__ pwb,
                   float* __restrict__ out)
{
    constexpr int CIC = 32;
    constexpr int PX  = 64;
    static_assert(CO / CPT == 16, "co groups must be 16");

    __shared__ float dwbuf[CIC * PX];
    __shared__ float wbuf[CIC * CO];

    const int t   = threadIdx.x;
    const int bid = blockIdx.x;
    const int jt  = bid & 3;
    const int i   = (bid >> 2) & 63;
    const int b   = bid >> 8;
    const int j0  = jt * PX;

    const int px_g = t & 15;
    const int co_g = t >> 4;
    const int co0  = co_g * CPT;
    const int p0   = px_g * 4;

    const int ci_local = t >> 3;
    const int g        = t & 7;
    const int jq       = j0 + g * 8;

    float acc[CPT][4];
    #pragma unroll
    for (int ii = 0; ii < CPT; ++ii) {
        float bv = pwb[co0 + ii];
        #pragma unroll
        for (int jj = 0; jj < 4; ++jj) acc[ii][jj] = bv;
    }

    for (int cc = 0; cc < CI; cc += CIC) {
        __syncthreads();
        {
            const float* src = wT + (size_t)cc * CO;
            #pragma unroll
            for (int idx = t * 4; idx < CIC * CO; idx += 1024)
                *reinterpret_cast<float4*>(&wbuf[idx]) =
                    *reinterpret_cast<const float4*>(&src[idx]);
        }
        {
            const int ci = cc + ci_local;
            const float* wk = dww + ci * 9;
            float w[9];
            #pragma unroll
            for (int k = 0; k < 9; ++k) w[k] = wk[k];
            float o[8];
            float bv = dwb[ci];
            #pragma unroll
            for (int e = 0; e < 8; ++e) o[e] = bv;

            const float* xp = xin + ((size_t)b * CI + ci) * HW;
            #pragma unroll
            for (int di = -1; di <= 1; ++di) {
                int ii2 = i + di;
                if ((unsigned)ii2 < (unsigned)BH_) {
                    const float* xr = xp + (size_t)ii2 * BW_ + jq;
                    float v[10];
                    v[0] = (jq > 0) ? xr[-1] : 0.f;
                    float4 A = *reinterpret_cast<const float4*>(xr);
                    float4 Bq = *reinterpret_cast<const float4*>(xr + 4);
                    v[1] = A.x; v[2] = A.y; v[3] = A.z; v[4] = A.w;
                    v[5] = Bq.x; v[6] = Bq.y; v[7] = Bq.z; v[8] = Bq.w;
                    v[9] = (jq + 8 < BW_) ? xr[8] : 0.f;
                    const float w0 = w[(di + 1) * 3 + 0];
                    const float w1 = w[(di + 1) * 3 + 1];
                    const float w2 = w[(di + 1) * 3 + 2];
                    #pragma unroll
                    for (int e = 0; e < 8; ++e)
                        o[e] += w0 * v[e] + w1 * v[e + 1] + w2 * v[e + 2];
                }
            }
            float4* dst = reinterpret_cast<float4*>(&dwbuf[ci_local * PX + g * 8]);
            dst[0] = make_float4(o[0], o[1], o[2], o[3]);
            dst[1] = make_float4(o[4], o[5], o[6], o[7]);
        }
        __syncthreads();

        #pragma unroll 4
        for (int k = 0; k < CIC; ++k) {
            float4 dq = *reinterpret_cast<const float4*>(&dwbuf[k * PX + p0]);
            float dv[4] = {dq.x, dq.y, dq.z, dq.w};
            float wv2[CPT];
            if constexpr (CPT == 2) {
                float2 wq = *reinterpret_cast<const float2*>(&wbuf[k * CO + co0]);
                wv2[0] = wq.x; wv2[1] = wq.y;
            } else {
                float4 wq = *reinterpret_cast<const float4*>(&wbuf[k * CO + co0]);
                #pragma unroll
                for (int ii = 0; ii < CPT && ii < 4; ++ii) wv2[ii] = (&wq.x)[ii];
            }
            #pragma unroll
            for (int ii = 0; ii < CPT; ++ii)
                #pragma unroll
                for (int jj = 0; jj < 4; ++jj)
                    acc[ii][jj] += wv2[ii] * dv[jj];
        }
    }

    #pragma unroll
    for (int ii = 0; ii < CPT; ++ii) {
        float4 v;
        v.x = fmaxf(acc[ii][0], 0.f);
        v.y = fmaxf(acc[ii][1], 0.f);
        v.z = fmaxf(acc[ii][2], 0.f);
        v.w = fmaxf(acc[ii][3], 0.f);
        float* op = out + (((size_t)b * CO + co0 + ii) * BH_ + i) * BW_ + j0 + p0;
        *reinterpret_cast<float4*>(op) = v;
    }
}

// ---------------------------------------------------------------------------
// Final fused kernel (unchanged from round 3): dw4 + pw(32->9) + softmax +
// char_attn + dynamic 3x3 conv with att in registers.
// ---------------------------------------------------------------------------
__global__ __launch_bounds__(256, 4)
void final_kernel(const float* __restrict__ x,
                  const float* __restrict__ a3,
                  const float* __restrict__ dww,
                  const float* __restrict__ dwb,
                  const float* __restrict__ pww,
                  const float* __restrict__ pwb,
                  float* __restrict__ out,
                  float* __restrict__ chat)
{
    constexpr int PX = 64;
    __shared__ float dwbuf[32 * PX];
    __shared__ float attL[9][PX];

    const int t   = threadIdx.x;
    const int bid = blockIdx.x;
    const int jt  = bid & 3;
    const int i   = (bid >> 2) & 63;
    const int b   = bid >> 8;
    const int j0  = jt * PX;
    const int g   = t & 7;
    const int jq  = j0 + g * 8;

    {
        const int ci = t >> 3;
        const float* wk = dww + ci * 9;
        float w[9];
        #pragma unroll
        for (int k = 0; k < 9; ++k) w[k] = wk[k];
        float o[8];
        float bv = dwb[ci];
        #pragma unroll
        for (int e = 0; e < 8; ++e) o[e] = bv;

        const float* xp = a3 + ((size_t)b * 32 + ci) * HW;
        #pragma unroll
        for (int di = -1; di <= 1; ++di) {
            int ii2 = i + di;
            if ((unsigned)ii2 < (unsigned)BH_) {
                const float* xr = xp + (size_t)ii2 * BW_ + jq;
                float v[10];
                v[0] = (jq > 0) ? xr[-1] : 0.f;
                float4 A = *reinterpret_cast<const float4*>(xr);
                float4 Bq = *reinterpret_cast<const float4*>(xr + 4);
                v[1] = A.x; v[2] = A.y; v[3] = A.z; v[4] = A.w;
                v[5] = Bq.x; v[6] = Bq.y; v[7] = Bq.z; v[8] = Bq.w;
                v[9] = (jq + 8 < BW_) ? xr[8] : 0.f;
                const float w0 = w[(di + 1) * 3 + 0];
                const float w1 = w[(di + 1) * 3 + 1];
                const float w2 = w[(di + 1) * 3 + 2];
                #pragma unroll
                for (int e = 0; e < 8; ++e)
                    o[e] += w0 * v[e] + w1 * v[e + 1] + w2 * v[e + 2];
            }
        }
        float4* dst = reinterpret_cast<float4*>(&dwbuf[(t >> 3) * PX + g * 8]);
        dst[0] = make_float4(o[0], o[1], o[2], o[3]);
        dst[1] = make_float4(o[4], o[5], o[6], o[7]);
    }
    __syncthreads();

    for (int idx = t; idx < 9 * PX; idx += 256) {
        int co = idx >> 6;
        int px = idx & 63;
        float acc = pwb[co];
        #pragma unroll
        for (int ci = 0; ci < 32; ++ci)
            acc += pww[co * 32 + ci] * dwbuf[ci * PX + px];
        attL[co][px] = acc;
    }
    __syncthreads();

    if (t < PX) {
        float v[9];
        float m = -1e30f;
        #pragma unroll
        for (int k = 0; k < 9; ++k) { v[k] = attL[k][t]; m = fmaxf(m, v[k]); }
        float s = 0.f;
        #pragma unroll
        for (int k = 0; k < 9; ++k) { v[k] = __expf(v[k] - m); s += v[k]; }
        float inv = 1.f / s;
        #pragma unroll
        for (int k = 0; k < 9; ++k) attL[k][t] = v[k] * inv;
    }
    __syncthreads();

    {
        size_t base = (((size_t)b * BH_ + i) * BW_ + j0) * 9;
        for (int idx = t; idx < PX * 9; idx += 256)
            chat[base + idx] = attL[idx % 9][idx / 9];
    }

    float ar[9][8];
    #pragma unroll
    for (int k = 0; k < 9; ++k) {
        float4 a0 = *reinterpret_cast<const float4*>(&attL[k][g * 8]);
        float4 a1 = *reinterpret_cast<const float4*>(&attL[k][g * 8 + 4]);
        ar[k][0] = a0.x; ar[k][1] = a0.y; ar[k][2] = a0.z; ar[k][3] = a0.w;
        ar[k][4] = a1.x; ar[k][5] = a1.y; ar[k][6] = a1.z; ar[k][7] = a1.w;
    }

    const int c0 = t >> 3;
    for (int c = c0; c < 256; c += 32) {
        const float* xp = x + ((size_t)b * 256 + c) * HW;
        float v3[3][10];
        #pragma unroll
        for (int di = 0; di < 3; ++di) {
            int ii2 = i + di - 1;
            if ((unsigned)ii2 < (unsigned)BH_) {
                const float* xr = xp + (size_t)ii2 * BW_ + jq;
                v3[di][0] = (jq > 0) ? xr[-1] : 0.f;
                float4 A = *reinterpret_cast<const float4*>(xr);
                float4 Bq = *reinterpret_cast<const float4*>(xr + 4);
                v3[di][1] = A.x; v3[di][2] = A.y; v3[di][3] = A.z; v3[di][4] = A.w;
                v3[di][5] = Bq.x; v3[di][6] = Bq.y; v3[di][7] = Bq.z; v3[di][8] = Bq.w;
                v3[di][9] = (jq + 8 < BW_) ? xr[8] : 0.f;
            } else {
                #pragma unroll
                for (int e = 0; e < 10; ++e) v3[di][e] = 0.f;
            }
        }
        float o[8];
        #pragma unroll
        for (int e = 0; e < 8; ++e) o[e] = 0.f;
        #pragma unroll
        for (int di = 0; di < 3; ++di)
            #pragma unroll
            for (int dj = 0; dj < 3; ++dj)
                #pragma unroll
                for (int e = 0; e < 8; ++e)
                    o[e] += v3[di][e + dj] * ar[di * 3 + dj][e];
        float* op = out + ((size_t)b * 256 + c) * HW + (size_t)i * BW_ + jq;
        *reinterpret_cast<float4*>(op)     = make_float4(o[0], o[1], o[2], o[3]);
        *reinterpret_cast<float4*>(op + 4) = make_float4(o[4], o[5], o[6], o[7]);
    }
}

// ---------------------------------------------------------------------------
extern "C" void kernel_launch(void* const* d_in, const int* in_sizes, int n_in,
                              void* d_out, int out_size, void* d_ws, size_t ws_size,
                              hipStream_t stream)
{
    const float* x    = (const float*)d_in[0];
    const float* dw1w = (const float*)d_in[1];
    const float* dw1b = (const float*)d_in[2];
    const float* pw1w = (const float*)d_in[3];
    const float* pw1b = (const float*)d_in[4];
    const float* dw2w = (const float*)d_in[5];
    const float* dw2b = (const float*)d_in[6];
    const float* pw2w = (const float*)d_in[7];
    const float* pw2b = (const float*)d_in[8];
    const float* dw3w = (const float*)d_in[9];
    const float* dw3b = (const float*)d_in[10];
    const float* pw3w = (const float*)d_in[11];
    const float* pw3b = (const float*)d_in[12];
    const float* dw4w = (const float*)d_in[13];
    const float* dw4b = (const float*)d_in[14];
    const float* pw4w = (const float*)d_in[15];
    const float* pw4b = (const float*)d_in[16];

    float* outp = (float*)d_out;
    float* chat = outp + (size_t)8 * 256 * HW;

    // ws layout (bytes): wb1 bf16 65536 | wb2 bf16 16384 | wt3 f32 8192 | a1 | a2
    short* wb1 = (short*)d_ws;
    short* wb2 = wb1 + 128 * 256;
    float* wt3 = (float*)((char*)d_ws + 81920);
    float* abase = (float*)((char*)d_ws + 90112);

    int kmax = 1;
    for (int k = 8; k >= 1; k >>= 1) {
        size_t need = 90112 + (size_t)k * (128 + 64) * HW * sizeof(float);
        if (need <= ws_size) { kmax = k; break; }
    }
    float* a1 = abase;
    float* a2 = a1 + (size_t)kmax * 128 * HW;
    float* a3 = a1;   // layer-3 output reuses a1's (dead) space

    prep_kernel<<<(128 * 256 + 64 * 128 + 32 * 64 + 255) / 256, 256, 0, stream>>>(
        pw1w, pw2w, pw3w, wb1, wb2, wt3);

    for (int b0 = 0; b0 < 8; b0 += kmax) {
        int kc = (8 - b0 < kmax) ? (8 - b0) : kmax;
        const float* xb = x + (size_t)b0 * 256 * HW;
        int grid64 = kc * 256;

        dsconv_mfma<256, 128><<<grid64, 256, 0, stream>>>(
            xb, dw1w, dw1b, wb1, pw1b, a1);
        dsconv_mfma<128, 64><<<grid64, 256, 0, stream>>>(
            a1, dw2w, dw2b, wb2, pw2b, a2);
        dsconv_kernel<64, 32, 2><<<grid64, 256, 0, stream>>>(
            a2, dw3w, dw3b, wt3, pw3b, a3);
        final_kernel<<<grid64, 256, 0, stream>>>(
            xb, a3, dw4w, dw4b, pw4w, pw4b,
            outp + (size_t)b0 * 256 * HW, chat + (size_t)b0 * HW * 9);
    }
}

// Round 5
// 282.684 us; speedup vs baseline: 3.1928x; 1.0035x over previous
//
#include <hip/hip_runtime.h>
#include <math.h>

// Problem constants (setup_inputs): B=8, C=256, H=64, W=256
#define BH_ 64
#define BW_ 256
constexpr size_t HW = (size_t)BH_ * BW_;   // 16384

using f32x4  = __attribute__((ext_vector_type(4))) float;
using short8 = __attribute__((ext_vector_type(8))) short;

__device__ __forceinline__ short f2bf(float f) {
    unsigned u = __float_as_uint(f);
    u += 0x7fffu + ((u >> 16) & 1u);     // RNE to bf16
    return (short)(u >> 16);
}

// ---------------------------------------------------------------------------
// Prep: pw1/pw2 -> bf16 (same (CO,CI) layout, k-contiguous for MFMA B);
//       pw3 -> fp32 transposed (CI,CO) for the fp32 layer-3 kernel.
// ---------------------------------------------------------------------------
__global__ __launch_bounds__(256)
void prep_kernel(const float* __restrict__ p1,   // (128,256)
                 const float* __restrict__ p2,   // (64,128)
                 const float* __restrict__ p3,   // (32,64)
                 short* __restrict__ wb1,        // (128,256) bf16
                 short* __restrict__ wb2,        // (64,128) bf16
                 float* __restrict__ wt3)        // (64,32) f32
{
    int idx = blockIdx.x * 256 + threadIdx.x;
    if (idx < 128 * 256) {
        wb1[idx] = f2bf(p1[idx]);
    } else if (idx < 128 * 256 + 64 * 128) {
        int r = idx - 128 * 256;
        wb2[r] = f2bf(p2[r]);
    } else if (idx < 128 * 256 + 64 * 128 + 32 * 64) {
        int r = idx - (128 * 256 + 64 * 128);
        int ci = r / 32, co = r % 32;
        wt3[r] = p3[co * 64 + ci];
    }
}

// ---------------------------------------------------------------------------
// MFMA depthwise-separable layer (bf16 GEMM, fp32 dw): layers 1 and 2.
// Software-pipelined: double-buffered A/B LDS tiles, ONE barrier per chunk.
// Per iteration: issue global loads for chunk c+1 (registers) -> MFMA(c)
// from LDS -> dw-compute(c+1) -> LDS stores(c+1) -> barrier. HBM latency of
// the prefetch hides under the MFMA + ds_read phase.
// Tile: 64 px of one row x CO. A=[px][ci] bf16 pad-40, B=[co][ci] pad-40,
// both XOR-swizzled (^((row>>3&7)<<3) shorts).
// mfma_f32_16x16x32_bf16: A m=lane&15,k=(lane>>4)*8+e; B n=lane&15 same k;
// D col(n)=lane&15, row(m)=(lane>>4)*4+r.
// ---------------------------------------------------------------------------
template<int CI, int CO>
__global__ __launch_bounds__(256, 4)
void dsconv_mfma(const float* __restrict__ xin,   // (kc, CI, H, W)
                 const float* __restrict__ dww,   // (CI, 9)
                 const float* __restrict__ dwb,   // (CI)
                 const short* __restrict__ wBf,   // (CO, CI) bf16
                 const float* __restrict__ pwb,   // (CO)
                 float* __restrict__ out)         // (kc, CO, H, W)
{
    constexpr int CIC = 32;
    constexpr int PX  = 64;
    constexpr int NT  = CO / 16;
    constexpr int WNT = NT / 4;            // n-tiles per wave (2 L1, 1 L2)
    constexpr int ST  = 40;                // padded row stride in shorts
    constexpr int NC  = CI / CIC;          // chunks (8 L1, 4 L2)
    constexpr int SPT = (CO * CIC) / 256;  // B shorts/thread (16 L1, 8 L2)
    constexpr int TPR = CIC / SPT;         // B threads/row
    constexpr int NB8 = SPT / 8;           // B short8s/thread
    static_assert(NT % 4 == 0 && CI % CIC == 0, "geometry");

    __shared__ short Abuf[2][PX * ST];     // 2 x 5 KB
    __shared__ short Bbuf[2][CO * ST];     // 2 x 10/5 KB

    const int t    = threadIdx.x;
    const int w    = t >> 6;
    const int lane = t & 63;
    const int bid  = blockIdx.x;
    const int jt   = bid & 3;              // W/64 = 4
    const int i    = (bid >> 2) & 63;      // H
    const int b    = bid >> 8;
    const int j0   = jt * PX;

    // dw mapping: one ci x 8 px per thread
    const int ci_l = t >> 3;               // 0..31
    const int g    = t & 7;
    const int jq   = j0 + g * 8;
    const bool vtop = (i > 0), vbot = (i < BH_ - 1);

    // B staging addressing (constant across chunks)
    const int bco   = t / TPR;
    const int bsub  = t % TPR;
    const int bswz  = ((bco >> 3) & 7) << 3;
    const int bbase = bco * ST + bsub * SPT;

    // mfma lane coords
    const int lm = lane & 15;
    const int kb = lane >> 4;

    f32x4 acc[4][WNT];
    #pragma unroll
    for (int q = 0; q < WNT; ++q) {
        float bv = pwb[(w * WNT + q) * 16 + lm];
        #pragma unroll
        for (int mt = 0; mt < 4; ++mt) {
            f32x4 z = {bv, bv, bv, bv};
            acc[mt][q] = z;
        }
    }

    // ---- pipeline registers ----
    float  xw[3][10];      // x windows for next chunk
    float  wv9[9];         // dw weights
    float  dwbv;           // dw bias
    short8 bst[NB8];       // B stage

    auto LOADX = [&](int cc) {
        const int ci = cc + ci_l;
        const float* xp = xin + ((size_t)b * CI + ci) * HW;
        #pragma unroll
        for (int di = 0; di < 3; ++di) {
            const bool ok = (di == 0) ? vtop : (di == 2) ? vbot : true;
            if (ok) {
                const float* xr = xp + (size_t)(i + di - 1) * BW_ + jq;
                xw[di][0] = (jq > 0) ? xr[-1] : 0.f;
                float4 A = *reinterpret_cast<const float4*>(xr);
                float4 Bq = *reinterpret_cast<const float4*>(xr + 4);
                xw[di][1] = A.x; xw[di][2] = A.y; xw[di][3] = A.z; xw[di][4] = A.w;
                xw[di][5] = Bq.x; xw[di][6] = Bq.y; xw[di][7] = Bq.z; xw[di][8] = Bq.w;
                xw[di][9] = (jq + 8 < BW_) ? xr[8] : 0.f;
            } else {
                #pragma unroll
                for (int e = 0; e < 10; ++e) xw[di][e] = 0.f;
            }
        }
        const float* wkp = dww + ci * 9;
        #pragma unroll
        for (int k = 0; k < 9; ++k) wv9[k] = wkp[k];
        dwbv = dwb[ci];
    };

    auto LOADB = [&](int cc) {
        const short* src = wBf + (size_t)bco * CI + cc + bsub * SPT;
        #pragma unroll
        for (int jj = 0; jj < NB8; ++jj)
            bst[jj] = *reinterpret_cast<const short8*>(&src[jj * 8]);
    };

    auto STORE = [&](int nb) {
        // B stage -> LDS (swizzled)
        #pragma unroll
        for (int jj = 0; jj < NB8; ++jj)
            *reinterpret_cast<short8*>(&Bbuf[nb][(bbase + jj * 8) ^ bswz]) = bst[jj];
        // dw compute from registers -> A LDS (bf16, swizzled scatter)
        float o[8];
        #pragma unroll
        for (int e = 0; e < 8; ++e) o[e] = dwbv;
        #pragma unroll
        for (int di = 0; di < 3; ++di) {
            const float w0 = wv9[di * 3 + 0];
            const float w1 = wv9[di * 3 + 1];
            const float w2 = wv9[di * 3 + 2];
            #pragma unroll
            for (int e = 0; e < 8; ++e)
                o[e] += w0 * xw[di][e] + w1 * xw[di][e + 1] + w2 * xw[di][e + 2];
        }
        #pragma unroll
        for (int e = 0; e < 8; ++e) {
            int px = g * 8 + e;
            int sa = (px * ST + ci_l) ^ (((px >> 3) & 7) << 3);
            Abuf[nb][sa] = f2bf(o[e]);
        }
    };

    auto MFMASTEP = [&](int nb) {
        short8 bfrag[WNT];
        #pragma unroll
        for (int q = 0; q < WNT; ++q) {
            int co = (w * WNT + q) * 16 + lm;
            int sa = (co * ST + kb * 8) ^ (((co >> 3) & 7) << 3);
            bfrag[q] = *reinterpret_cast<const short8*>(&Bbuf[nb][sa]);
        }
        #pragma unroll
        for (int mt = 0; mt < 4; ++mt) {
            int px = mt * 16 + lm;
            int sa = (px * ST + kb * 8) ^ (((px >> 3) & 7) << 3);
            short8 af = *reinterpret_cast<const short8*>(&Abuf[nb][sa]);
            #pragma unroll
            for (int q = 0; q < WNT; ++q)
                acc[mt][q] = __builtin_amdgcn_mfma_f32_16x16x32_bf16(
                    af, bfrag[q], acc[mt][q], 0, 0, 0);
        }
    };

    // ---- prologue: chunk 0 ----
    LOADX(0); LOADB(0);
    STORE(0);
    __syncthreads();

    // ---- pipelined main loop: one barrier per chunk ----
    for (int c = 0; c < NC; ++c) {
        if (c + 1 < NC) { LOADX((c + 1) * CIC); LOADB((c + 1) * CIC); }
        MFMASTEP(c & 1);
        if (c + 1 < NC) {
            STORE((c + 1) & 1);
            __syncthreads();
        }
    }

    // ---- epilogue: ReLU + float4 stores (coalesced per co line) ----
    #pragma unroll
    for (int mt = 0; mt < 4; ++mt) {
        #pragma unroll
        for (int q = 0; q < WNT; ++q) {
            int co = (w * WNT + q) * 16 + lm;
            float* op = out + (((size_t)b * CO + co) * BH_ + i) * BW_
                        + j0 + mt * 16 + kb * 4;
            float4 v;
            v.x = fmaxf(acc[mt][q][0], 0.f);
            v.y = fmaxf(acc[mt][q][1], 0.f);
            v.z = fmaxf(acc[mt][q][2], 0.f);
            v.w = fmaxf(acc[mt][q][3], 0.f);
            *reinterpret_cast<float4*>(op) = v;
        }
    }
}

// ---------------------------------------------------------------------------
// fp32 depthwise-separable layer (layer 3 only).
// ---------------------------------------------------------------------------
template<int CI, int CO, int CPT>
__global__ __launch_bounds__(256, 4)
void dsconv_kernel(const float* __restrict__ xin,
                   const float* __restrict__ dww,
                   const float* __restrict__ dwb,
                   const float* __restrict__ wT,    // (CI, CO) transposed pw
                   const float* __restrict__ pwb,
                   float* __restrict__ out)
{
    constexpr int CIC = 32;
    constexpr int PX  = 64;
    static_assert(CO / CPT == 16, "co groups must be 16");

    __shared__ float dwbuf[CIC * PX];
    __shared__ float wbuf[CIC * CO];

    const int t   = threadIdx.x;
    const int bid = blockIdx.x;
    const int jt  = bid & 3;
    const int i   = (bid >> 2) & 63;
    const int b   = bid >> 8;
    const int j0  = jt * PX;

    const int px_g = t & 15;
    const int co_g = t >> 4;
    const int co0  = co_g * CPT;
    const int p0   = px_g * 4;

    const int ci_local = t >> 3;
    const int g        = t & 7;
    const int jq       = j0 + g * 8;

    float acc[CPT][4];
    #pragma unroll
    for (int ii = 0; ii < CPT; ++ii) {
        float bv = pwb[co0 + ii];
        #pragma unroll
        for (int jj = 0; jj < 4; ++jj) acc[ii][jj] = bv;
    }

    for (int cc = 0; cc < CI; cc += CIC) {
        __syncthreads();
        {
            const float* src = wT + (size_t)cc * CO;
            #pragma unroll
            for (int idx = t * 4; idx < CIC * CO; idx += 1024)
                *reinterpret_cast<float4*>(&wbuf[idx]) =
                    *reinterpret_cast<const float4*>(&src[idx]);
        }
        {
            const int ci = cc + ci_local;
            const float* wk = dww + ci * 9;
            float w[9];
            #pragma unroll
            for (int k = 0; k < 9; ++k) w[k] = wk[k];
            float o[8];
            float bv = dwb[ci];
            #pragma unroll
            for (int e = 0; e < 8; ++e) o[e] = bv;

            const float* xp = xin + ((size_t)b * CI + ci) * HW;
            #pragma unroll
            for (int di = -1; di <= 1; ++di) {
                int ii2 = i + di;
                if ((unsigned)ii2 < (unsigned)BH_) {
                    const float* xr = xp + (size_t)ii2 * BW_ + jq;
                    float v[10];
                    v[0] = (jq > 0) ? xr[-1] : 0.f;
                    float4 A = *reinterpret_cast<const float4*>(xr);
                    float4 Bq = *reinterpret_cast<const float4*>(xr + 4);
                    v[1] = A.x; v[2] = A.y; v[3] = A.z; v[4] = A.w;
                    v[5] = Bq.x; v[6] = Bq.y; v[7] = Bq.z; v[8] = Bq.w;
                    v[9] = (jq + 8 < BW_) ? xr[8] : 0.f;
                    const float w0 = w[(di + 1) * 3 + 0];
                    const float w1 = w[(di + 1) * 3 + 1];
                    const float w2 = w[(di + 1) * 3 + 2];
                    #pragma unroll
                    for (int e = 0; e < 8; ++e)
                        o[e] += w0 * v[e] + w1 * v[e + 1] + w2 * v[e + 2];
                }
            }
            float4* dst = reinterpret_cast<float4*>(&dwbuf[ci_local * PX + g * 8]);
            dst[0] = make_float4(o[0], o[1], o[2], o[3]);
            dst[1] = make_float4(o[4], o[5], o[6], o[7]);
        }
        __syncthreads();

        #pragma unroll 4
        for (int k = 0; k < CIC; ++k) {
            float4 dq = *reinterpret_cast<const float4*>(&dwbuf[k * PX + p0]);
            float dv[4] = {dq.x, dq.y, dq.z, dq.w};
            float wv2[CPT];
            if constexpr (CPT == 2) {
                float2 wq = *reinterpret_cast<const float2*>(&wbuf[k * CO + co0]);
                wv2[0] = wq.x; wv2[1] = wq.y;
            } else {
                float4 wq = *reinterpret_cast<const float4*>(&wbuf[k * CO + co0]);
                #pragma unroll
                for (int ii = 0; ii < CPT && ii < 4; ++ii) wv2[ii] = (&wq.x)[ii];
            }
            #pragma unroll
            for (int ii = 0; ii < CPT; ++ii)
                #pragma unroll
                for (int jj = 0; jj < 4; ++jj)
                    acc[ii][jj] += wv2[ii] * dv[jj];
        }
    }

    #pragma unroll
    for (int ii = 0; ii < CPT; ++ii) {
        float4 v;
        v.x = fmaxf(acc[ii][0], 0.f);
        v.y = fmaxf(acc[ii][1], 0.f);
        v.z = fmaxf(acc[ii][2], 0.f);
        v.w = fmaxf(acc[ii][3], 0.f);
        float* op = out + (((size_t)b * CO + co0 + ii) * BH_ + i) * BW_ + j0 + p0;
        *reinterpret_cast<float4*>(op) = v;
    }
}

// ---------------------------------------------------------------------------
// Final fused kernel: dw4 + pw(32->9) + softmax + char_attn + dynamic conv.
// ---------------------------------------------------------------------------
__global__ __launch_bounds__(256, 4)
void final_kernel(const float* __restrict__ x,
                  const float* __restrict__ a3,
                  const float* __restrict__ dww,
                  const float* __restrict__ dwb,
                  const float* __restrict__ pww,
                  const float* __restrict__ pwb,
                  float* __restrict__ out,
                  float* __restrict__ chat)
{
    constexpr int PX = 64;
    __shared__ float dwbuf[32 * PX];
    __shared__ float attL[9][PX];

    const int t   = threadIdx.x;
    const int bid = blockIdx.x;
    const int jt  = bid & 3;
    const int i   = (bid >> 2) & 63;
    const int b   = bid >> 8;
    const int j0  = jt * PX;
    const int g   = t & 7;
    const int jq  = j0 + g * 8;

    {
        const int ci = t >> 3;
        const float* wk = dww + ci * 9;
        float w[9];
        #pragma unroll
        for (int k = 0; k < 9; ++k) w[k] = wk[k];
        float o[8];
        float bv = dwb[ci];
        #pragma unroll
        for (int e = 0; e < 8; ++e) o[e] = bv;

        const float* xp = a3 + ((size_t)b * 32 + ci) * HW;
        #pragma unroll
        for (int di = -1; di <= 1; ++di) {
            int ii2 = i + di;
            if ((unsigned)ii2 < (unsigned)BH_) {
                const float* xr = xp + (size_t)ii2 * BW_ + jq;
                float v[10];
                v[0] = (jq > 0) ? xr[-1] : 0.f;
                float4 A = *reinterpret_cast<const float4*>(xr);
                float4 Bq = *reinterpret_cast<const float4*>(xr + 4);
                v[1] = A.x; v[2] = A.y; v[3] = A.z; v[4] = A.w;
                v[5] = Bq.x; v[6] = Bq.y; v[7] = Bq.z; v[8] = Bq.w;
                v[9] = (jq + 8 < BW_) ? xr[8] : 0.f;
                const float w0 = w[(di + 1) * 3 + 0];
                const float w1 = w[(di + 1) * 3 + 1];
                const float w2 = w[(di + 1) * 3 + 2];
                #pragma unroll
                for (int e = 0; e < 8; ++e)
                    o[e] += w0 * v[e] + w1 * v[e + 1] + w2 * v[e + 2];
            }
        }
        float4* dst = reinterpret_cast<float4*>(&dwbuf[(t >> 3) * PX + g * 8]);
        dst[0] = make_float4(o[0], o[1], o[2], o[3]);
        dst[1] = make_float4(o[4], o[5], o[6], o[7]);
    }
    __syncthreads();

    for (int idx = t; idx < 9 * PX; idx += 256) {
        int co = idx >> 6;
        int px = idx & 63;
        float acc = pwb[co];
        #pragma unroll
        for (int ci = 0; ci < 32; ++ci)
            acc += pww[co * 32 + ci] * dwbuf[ci * PX + px];
        attL[co][px] = acc;
    }
    __syncthreads();

    if (t < PX) {
        float v[9];
        float m = -1e30f;
        #pragma unroll
        for (int k = 0; k < 9; ++k) { v[k] = attL[k][t]; m = fmaxf(m, v[k]); }
        float s = 0.f;
        #pragma unroll
        for (int k = 0; k < 9; ++k) { v[k] = __expf(v[k] - m); s += v[k]; }
        float inv = 1.f / s;
        #pragma unroll
        for (int k = 0; k < 9; ++k) attL[k][t] = v[k] * inv;
    }
    __syncthreads();

    {
        size_t base = (((size_t)b * BH_ + i) * BW_ + j0) * 9;
        for (int idx = t; idx < PX * 9; idx += 256)
            chat[base + idx] = attL[idx % 9][idx / 9];
    }

    float ar[9][8];
    #pragma unroll
    for (int k = 0; k < 9; ++k) {
        float4 a0 = *reinterpret_cast<const float4*>(&attL[k][g * 8]);
        float4 a1 = *reinterpret_cast<const float4*>(&attL[k][g * 8 + 4]);
        ar[k][0] = a0.x; ar[k][1] = a0.y; ar[k][2] = a0.z; ar[k][3] = a0.w;
        ar[k][4] = a1.x; ar[k][5] = a1.y; ar[k][6] = a1.z; ar[k][7] = a1.w;
    }

    const int c0 = t >> 3;
    for (int c = c0; c < 256; c += 32) {
        const float* xp = x + ((size_t)b * 256 + c) * HW;
        float v3[3][10];
        #pragma unroll
        for (int di = 0; di < 3; ++di) {
            int ii2 = i + di - 1;
            if ((unsigned)ii2 < (unsigned)BH_) {
                const float* xr = xp + (size_t)ii2 * BW_ + jq;
                v3[di][0] = (jq > 0) ? xr[-1] : 0.f;
                float4 A = *reinterpret_cast<const float4*>(xr);
                float4 Bq = *reinterpret_cast<const float4*>(xr + 4);
                v3[di][1] = A.x; v3[di][2] = A.y; v3[di][3] = A.z; v3[di][4] = A.w;
                v3[di][5] = Bq.x; v3[di][6] = Bq.y; v3[di][7] = Bq.z; v3[di][8] = Bq.w;
                v3[di][9] = (jq + 8 < BW_) ? xr[8] : 0.f;
            } else {
                #pragma unroll
                for (int e = 0; e < 10; ++e) v3[di][e] = 0.f;
            }
        }
        float o[8];
        #pragma unroll
        for (int e = 0; e < 8; ++e) o[e] = 0.f;
        #pragma unroll
        for (int di = 0; di < 3; ++di)
            #pragma unroll
            for (int dj = 0; dj < 3; ++dj)
                #pragma unroll
                for (int e = 0; e < 8; ++e)
                    o[e] += v3[di][e + dj] * ar[di * 3 + dj][e];
        float* op = out + ((size_t)b * 256 + c) * HW + (size_t)i * BW_ + jq;
        *reinterpret_cast<float4*>(op)     = make_float4(o[0], o[1], o[2], o[3]);
        *reinterpret_cast<float4*>(op + 4) = make_float4(o[4], o[5], o[6], o[7]);
    }
}

// ---------------------------------------------------------------------------
extern "C" void kernel_launch(void* const* d_in, const int* in_sizes, int n_in,
                              void* d_out, int out_size, void* d_ws, size_t ws_size,
                              hipStream_t stream)
{
    const float* x    = (const float*)d_in[0];
    const float* dw1w = (const float*)d_in[1];
    const float* dw1b = (const float*)d_in[2];
    const float* pw1w = (const float*)d_in[3];
    const float* pw1b = (const float*)d_in[4];
    const float* dw2w = (const float*)d_in[5];
    const float* dw2b = (const float*)d_in[6];
    const float* pw2w = (const float*)d_in[7];
    const float* pw2b = (const float*)d_in[8];
    const float* dw3w = (const float*)d_in[9];
    const float* dw3b = (const float*)d_in[10];
    const float* pw3w = (const float*)d_in[11];
    const float* pw3b = (const float*)d_in[12];
    const float* dw4w = (const float*)d_in[13];
    const float* dw4b = (const float*)d_in[14];
    const float* pw4w = (const float*)d_in[15];
    const float* pw4b = (const float*)d_in[16];

    float* outp = (float*)d_out;
    float* chat = outp + (size_t)8 * 256 * HW;

    // ws layout (bytes): wb1 bf16 65536 | wb2 bf16 16384 | wt3 f32 8192 | a1 | a2
    short* wb1 = (short*)d_ws;
    short* wb2 = wb1 + 128 * 256;
    float* wt3 = (float*)((char*)d_ws + 81920);
    float* abase = (float*)((char*)d_ws + 90112);

    int kmax = 1;
    for (int k = 8; k >= 1; k >>= 1) {
        size_t need = 90112 + (size_t)k * (128 + 64) * HW * sizeof(float);
        if (need <= ws_size) { kmax = k; break; }
    }
    float* a1 = abase;
    float* a2 = a1 + (size_t)kmax * 128 * HW;
    float* a3 = a1;   // layer-3 output reuses a1's (dead) space

    prep_kernel<<<(128 * 256 + 64 * 128 + 32 * 64 + 255) / 256, 256, 0, stream>>>(
        pw1w, pw2w, pw3w, wb1, wb2, wt3);

    for (int b0 = 0; b0 < 8; b0 += kmax) {
        int kc = (8 - b0 < kmax) ? (8 - b0) : kmax;
        const float* xb = x + (size_t)b0 * 256 * HW;
        int grid64 = kc * 256;

        dsconv_mfma<256, 128><<<grid64, 256, 0, stream>>>(
            xb, dw1w, dw1b, wb1, pw1b, a1);
        dsconv_mfma<128, 64><<<grid64, 256, 0, stream>>>(
            a1, dw2w, dw2b, wb2, pw2b, a2);
        dsconv_kernel<64, 32, 2><<<grid64, 256, 0, stream>>>(
            a2, dw3w, dw3b, wt3, pw3b, a3);
        final_kernel<<<grid64, 256, 0, stream>>>(
            xb, a3, dw4w, dw4b, pw4w, pw4b,
            outp + (size_t)b0 * 256 * HW, chat + (size_t)b0 * HW * 9);
    }
}